// Round 8
// baseline (457.373 us; speedup 1.0000x reference)
//
#include <hip/hip_runtime.h>
#include <hip/hip_fp16.h>
#include <climits>

#define RR 32
#define R3 32768           // 32^3
#define NPTS 65536
#define NCH 64
#define NB 8

// ---------------- atomic-free reductions ----------------

// grid (64, NB), block 256; each block reduces 1024 points -> part[(b*64+blk)*3+axis]
__global__ void mean1_kernel(const float* __restrict__ coords, double* __restrict__ part) {
    __shared__ double ls[3][4];
    int b = blockIdx.y, blk = blockIdx.x;
    int t = threadIdx.x;
    const float* cb = coords + (size_t)b * 3 * NPTS;
    int base = blk * 1024 + t;
    double sx = 0.0, sy = 0.0, sz = 0.0;
#pragma unroll
    for (int k = 0; k < 4; k++) {
        int n = base + k * 256;
        sx += cb[n];
        sy += cb[NPTS + n];
        sz += cb[2 * NPTS + n];
    }
    for (int off = 32; off > 0; off >>= 1) {
        sx += __shfl_down(sx, off);
        sy += __shfl_down(sy, off);
        sz += __shfl_down(sz, off);
    }
    int wave = t >> 6;
    if ((t & 63) == 0) { ls[0][wave] = sx; ls[1][wave] = sy; ls[2][wave] = sz; }
    __syncthreads();
    if (t == 0) {
        part[((size_t)b * 64 + blk) * 3 + 0] = ls[0][0] + ls[0][1] + ls[0][2] + ls[0][3];
        part[((size_t)b * 64 + blk) * 3 + 1] = ls[1][0] + ls[1][1] + ls[1][2] + ls[1][3];
        part[((size_t)b * 64 + blk) * 3 + 2] = ls[2][0] + ls[2][1] + ls[2][2] + ls[2][3];
    }
}

// grid NB, block 64; combine 64 partials -> meanf[b*4+axis]
__global__ void mean2_kernel(const double* __restrict__ part, float* __restrict__ meanf) {
    int b = blockIdx.x, l = threadIdx.x;
    double sx = part[((size_t)b * 64 + l) * 3 + 0];
    double sy = part[((size_t)b * 64 + l) * 3 + 1];
    double sz = part[((size_t)b * 64 + l) * 3 + 2];
    for (int off = 32; off > 0; off >>= 1) {
        sx += __shfl_down(sx, off);
        sy += __shfl_down(sy, off);
        sz += __shfl_down(sz, off);
    }
    if (l == 0) {
        meanf[b * 4 + 0] = (float)(sx * (1.0 / NPTS));
        meanf[b * 4 + 1] = (float)(sy * (1.0 / NPTS));
        meanf[b * 4 + 2] = (float)(sz * (1.0 / NPTS));
    }
}

// grid (64, NB), block 256; partial max of squared dist -> partmax[b*64+blk]
__global__ void max1_kernel(const float* __restrict__ coords,
                            const float* __restrict__ meanf,
                            float* __restrict__ partmax) {
    __shared__ float ls[4];
    int b = blockIdx.y, blk = blockIdx.x;
    int t = threadIdx.x;
    float mx = meanf[b * 4 + 0], my = meanf[b * 4 + 1], mz = meanf[b * 4 + 2];
    const float* cb = coords + (size_t)b * 3 * NPTS;
    int base = blk * 1024 + t;
    float m = 0.0f;
#pragma unroll
    for (int k = 0; k < 4; k++) {
        int n = base + k * 256;
        float dx = cb[n] - mx;
        float dy = cb[NPTS + n] - my;
        float dz = cb[2 * NPTS + n] - mz;
        m = fmaxf(m, dx * dx + dy * dy + dz * dz);
    }
    for (int off = 32; off > 0; off >>= 1) m = fmaxf(m, __shfl_down(m, off));
    int wave = t >> 6;
    if ((t & 63) == 0) ls[wave] = m;
    __syncthreads();
    if (t == 0) partmax[b * 64 + blk] = fmaxf(fmaxf(ls[0], ls[1]), fmaxf(ls[2], ls[3]));
}

// grid NB, block 64; combine -> denom[b] = 2*sqrt(max)
__global__ void max2_kernel(const float* __restrict__ partmax, float* __restrict__ denom) {
    int b = blockIdx.x, l = threadIdx.x;
    float m = partmax[b * 64 + l];
    for (int off = 32; off > 0; off >>= 1) m = fmaxf(m, __shfl_down(m, off));
    if (l == 0) denom[b] = 2.0f * sqrtf(m);   // EPS = 0
}

// ---------------- sorted pipeline ----------------

__global__ void nc_vid_kernel(const float* __restrict__ coords,
                              const float* __restrict__ meanf,
                              const float* __restrict__ denomv,
                              float* __restrict__ ncout,
                              int* __restrict__ vid,
                              unsigned* __restrict__ cnt) {
    int b = blockIdx.y;
    int n = blockIdx.x * blockDim.x + threadIdx.x;
    float mx = meanf[b * 4 + 0], my = meanf[b * 4 + 1], mz = meanf[b * 4 + 2];
    float denom = denomv[b];
    const float* cb = coords + (size_t)b * 3 * NPTS;
    float dx = cb[n] - mx;
    float dy = cb[NPTS + n] - my;
    float dz = cb[2 * NPTS + n] - mz;
    float qx = fminf(fmaxf((dx / denom + 0.5f) * 32.0f, 0.0f), 31.0f);
    float qy = fminf(fmaxf((dy / denom + 0.5f) * 32.0f, 0.0f), 31.0f);
    float qz = fminf(fmaxf((dz / denom + 0.5f) * 32.0f, 0.0f), 31.0f);
    float* nb_ = ncout + (size_t)b * 3 * NPTS;
    nb_[n] = qx;
    nb_[NPTS + n] = qy;
    nb_[2 * NPTS + n] = qz;
    int flat = ((int)rintf(qx) * RR + (int)rintf(qy)) * RR + (int)rintf(qz);
    vid[b * NPTS + n] = flat;
    atomicAdd(&cnt[b * R3 + flat], 1u);
}

// Per-batch exclusive prefix over R3 voxels -> cursor. 1 block/batch.
__global__ __launch_bounds__(1024) void scan_kernel(const unsigned* __restrict__ cnt,
                                                    unsigned* __restrict__ cursor) {
    __shared__ unsigned buf[R3 + R3 / 32];   // skewed, 132 KB
    __shared__ unsigned ls[1024];
    int b = blockIdx.x;
    int t = threadIdx.x;
    const unsigned* c = cnt + b * R3;
    for (int i = t; i < R3; i += 1024) buf[i + (i >> 5)] = c[i];
    __syncthreads();
    int sb = t * 33;                         // SKEW(t*32 + k) = t*33 + k
    unsigned v[32];
    unsigned s = 0;
#pragma unroll
    for (int k = 0; k < 32; k++) {
        unsigned x = buf[sb + k];
        v[k] = s;
        s += x;
    }
    ls[t] = s;
    __syncthreads();
    for (int d = 1; d < 1024; d <<= 1) {
        unsigned x = (t >= d) ? ls[t - d] : 0u;
        __syncthreads();
        ls[t] += x;
        __syncthreads();
    }
    unsigned chunk_excl = (t == 0) ? 0u : ls[t - 1];
#pragma unroll
    for (int k = 0; k < 32; k++) buf[sb + k] = chunk_excl + v[k];
    __syncthreads();
    unsigned* cur = cursor + b * R3;
    for (int i = t; i < R3; i += 1024) cur[i] = buf[i + (i >> 5)];
}

// Transpose 64x64 feature tile AND scatter rows to sorted positions (fp16).
// After this kernel, cursor[v] = exclusive END of voxel v's sorted segment.
__global__ void permute_kernel(const float* __restrict__ feats,
                               const int* __restrict__ vid,
                               unsigned* __restrict__ cursor,
                               __half* __restrict__ ft,
                               int* __restrict__ vid_sorted) {
    __shared__ float tile[64][65];
    __shared__ int spos[64];
    int b  = blockIdx.y;
    int n0 = blockIdx.x * 64;
    int t  = threadIdx.x;

    if (t < 64) {
        int flat = vid[b * NPTS + n0 + t];
        int pos = (int)atomicAdd(&cursor[b * R3 + flat], 1u);
        spos[t] = pos;
        vid_sorted[b * NPTS + pos] = flat;
    }

    const float* fb = feats + (size_t)b * NCH * NPTS + n0;
    int i  = t & 63;
    int c0w = t >> 6;
#pragma unroll
    for (int iter = 0; iter < 16; iter++) {
        int c = iter * 4 + c0w;
        tile[i][c] = fb[(size_t)c * NPTS + i];
    }
    __syncthreads();

    int wave = t >> 6;
    int lane = t & 63;
    int hp = lane >> 5;              // which point of the pair
    int c0 = (lane & 31) * 2;        // channel pair
    __half* fbase = ft + (size_t)b * NPTS * NCH;
#pragma unroll
    for (int j = 0; j < 8; j++) {
        int p = wave * 16 + j * 2 + hp;
        __half2 hv = __floats2half2_rn(tile[p][c0], tile[p][c0 + 1]);
        *reinterpret_cast<__half2*>(fbase + (size_t)spos[p] * NCH + c0) = hv;
    }
}

// Fused segsum + normalize + transpose. One block per 64 consecutive voxels:
// since vid>>6 is a prefix of the sort key, those voxels' points are one
// CONTIGUOUS sorted range [cursor[v0-1], cursor[v0+63]). Reuses R5's proven
// chunk/run-accumulate structure (32 positions per half-wave, channel-pair
// per lane) but flushes into a skewed 16.6KB LDS tile instead of global
// ws_vox, then writes normalized transposed output directly to voxout.
// Eliminates: ws_vox (64MB memset + ~61MB atomic RMW + 128MB normalize IO).
// vs R4's failed bucket kernel: no v[64] preload (no scratch spill),
// skewed acc (conflict-free epilogue), balanced 64-voxel ranges.
__global__ void voxsum_kernel(const __half* __restrict__ ft,
                              const int* __restrict__ vid_sorted,
                              const unsigned* __restrict__ cursor,   // post-permute ends
                              const unsigned* __restrict__ cnt,
                              float* __restrict__ voxout) {
    __shared__ float acc[64 * 65];       // [qz][ch] skewed (+1): epilogue bank-free
    __shared__ float cinv[64];
    __shared__ int sv[257];
    int b  = blockIdx.y;
    int v0 = blockIdx.x * 64;
    int t  = threadIdx.x;

    for (int i = t; i < 64 * 65; i += 256) acc[i] = 0.0f;
    if (t < 64) cinv[t] = 1.0f / fmaxf((float)cnt[b * R3 + v0 + t], 1.0f);

    unsigned start = (v0 == 0) ? 0u : cursor[b * R3 + v0 - 1];
    unsigned end   = cursor[b * R3 + v0 + 63];
    __syncthreads();

    const int* vs = vid_sorted + (size_t)b * NPTS;
    int wave  = t >> 6;
    int lane  = t & 63;
    int chunk = wave * 2 + (lane >> 5);   // 0..7, 32 positions each
    int c0    = (lane & 31) * 2;          // channel pair
    int p0    = chunk * 32;

    for (unsigned tile0 = start; tile0 < end; tile0 += 256) {
        unsigned p = tile0 + t;
        sv[t] = (p < end) ? vs[p] : INT_MAX;
        if (t == 0)
            sv[256] = (tile0 + 256 < end) ? vs[tile0 + 256] : INT_MAX;
        __syncthreads();

        unsigned pg = tile0 + p0;
        const __half* fb = ft + ((size_t)b * NPTS + pg) * NCH + c0;

        float sx = 0.0f, sy = 0.0f;
        int vcur = sv[p0];
#pragma unroll
        for (int k = 0; k < 32; k++) {
            float fx = 0.0f, fy = 0.0f;
            if (pg + k < end) {
                __half2 h = *reinterpret_cast<const __half2*>(fb + (size_t)k * NCH);
                float2 f = __half22float2(h);
                fx = f.x; fy = f.y;
            }
            sx += fx;
            sy += fy;
            int vnext = sv[p0 + k + 1];   // p0+32 valid: sv has 257 entries
            if (vnext != vcur) {
                unsigned row = (unsigned)(vcur - v0);
                if (row < 64u) {
                    atomicAdd(&acc[row * 65 + c0], sx);
                    atomicAdd(&acc[row * 65 + c0 + 1], sy);
                }
                sx = 0.0f;
                sy = 0.0f;
                vcur = vnext;
            }
        }
        if (sx != 0.0f || sy != 0.0f) {   // run continues past chunk: partial
            unsigned row = (unsigned)(vcur - v0);
            if (row < 64u) {
                atomicAdd(&acc[row * 65 + c0], sx);
                atomicAdd(&acc[row * 65 + c0 + 1], sy);
            }
        }
        __syncthreads();                  // atomics drained before sv restage
    }

    // epilogue: voxout[b][c][v0+qz] = acc[qz][c] * cinv[qz]
    // lanes span qz 0..63 -> 256B contiguous stores; LDS read (qz*65+c)%32
    // = (qz+c)%32 -> 2 lanes/bank = free.
    float* dst = voxout + (size_t)b * NCH * R3 + v0;
    int qz = t & 63;
    int cw = t >> 6;
#pragma unroll
    for (int it = 0; it < 16; it++) {
        int c = it * 4 + cw;
        dst[(size_t)c * R3 + qz] = acc[qz * 65 + c] * cinv[qz];
    }
}

// ---------------- fallback: voxel-major atomics ----------------

__global__ void scatter_vm_kernel(const float* __restrict__ feats,
                                  const float* __restrict__ coords,
                                  const float* __restrict__ meanf,
                                  const float* __restrict__ denomv,
                                  float* __restrict__ ws_vox,
                                  float* __restrict__ ncout,
                                  float* __restrict__ cnt) {
    __shared__ float tile[64][65];
    __shared__ int   sflat[64];
    int b  = blockIdx.y;
    int n0 = blockIdx.x * 64;
    int t  = threadIdx.x;
    if (t < 64) {
        int n = n0 + t;
        float mx = meanf[b * 4 + 0], my = meanf[b * 4 + 1], mz = meanf[b * 4 + 2];
        float denom = denomv[b];
        const float* cb = coords + (size_t)b * 3 * NPTS;
        float dx = cb[n] - mx;
        float dy = cb[NPTS + n] - my;
        float dz = cb[2 * NPTS + n] - mz;
        float qx = fminf(fmaxf((dx / denom + 0.5f) * 32.0f, 0.0f), 31.0f);
        float qy = fminf(fmaxf((dy / denom + 0.5f) * 32.0f, 0.0f), 31.0f);
        float qz = fminf(fmaxf((dz / denom + 0.5f) * 32.0f, 0.0f), 31.0f);
        float* nb_ = ncout + (size_t)b * 3 * NPTS;
        nb_[n] = qx;
        nb_[NPTS + n] = qy;
        nb_[2 * NPTS + n] = qz;
        int flat = ((int)rintf(qx) * RR + (int)rintf(qy)) * RR + (int)rintf(qz);
        sflat[t] = flat;
        atomicAdd(&cnt[b * R3 + flat], 1.0f);
    }
    const float* fb = feats + (size_t)b * NCH * NPTS + n0;
    int i = t & 63;
    int c0 = t >> 6;
#pragma unroll
    for (int iter = 0; iter < 16; iter++) {
        int c = iter * 4 + c0;
        tile[i][c] = fb[(size_t)c * NPTS + i];
    }
    __syncthreads();
    int wave = t >> 6;
    int lane = t & 63;
#pragma unroll
    for (int k = 0; k < 16; k++) {
        int p = wave * 16 + k;
        float v = tile[p][lane];
        size_t base = ((size_t)b * R3 + sflat[p]) * NCH;
        atomicAdd(&ws_vox[base + lane], v);
    }
}

__global__ void normalize_tf_kernel(const float* __restrict__ ws_vox,
                                    const float* __restrict__ cnt,
                                    float* __restrict__ voxout) {
    __shared__ float tile[64][65];
    __shared__ float cinv[64];
    int b  = blockIdx.y;
    int v0 = blockIdx.x * 64;
    int t  = threadIdx.x;
    if (t < 64) cinv[t] = 1.0f / fmaxf(cnt[b * R3 + v0 + t], 1.0f);
    __syncthreads();
    const float* src = ws_vox + ((size_t)b * R3 + v0) * NCH;
    int c = t & 63;
    int w = t >> 6;
#pragma unroll
    for (int iter = 0; iter < 16; iter++) {
        int vi = iter * 4 + w;
        tile[c][vi] = src[(size_t)vi * NCH + c] * cinv[vi];
    }
    __syncthreads();
    float* dst = voxout + (size_t)b * NCH * R3 + v0;
    int vi = t & 63;
#pragma unroll
    for (int iter = 0; iter < 16; iter++) {
        int cc = iter * 4 + w;
        dst[(size_t)cc * R3 + vi] = tile[cc][vi];
    }
}

extern "C" void kernel_launch(void* const* d_in, const int* in_sizes, int n_in,
                              void* d_out, int out_size, void* d_ws, size_t ws_size,
                              hipStream_t stream) {
    const float* feats  = (const float*)d_in[0];   // [8,64,65536]
    const float* coords = (const float*)d_in[1];   // [8,3,65536]
    float* out = (float*)d_out;
    float* voxout = out;                                   // [8,64,32768]
    float* ncout  = out + (size_t)NB * NCH * R3;           // [8,3,65536]

    // small scratch (no zeroing needed — all plain-written before read)
    double* part    = (double*)d_ws;                               // [NB*64*3] = 12 KB
    float*  partmax = (float*)((char*)d_ws + 12544);               // [NB*64]   = 2 KB
    float*  meanf   = (float*)((char*)d_ws + 14592);               // [NB*4]
    float*  denomv  = (float*)((char*)d_ws + 14720);               // [NB]

    const size_t off_cnt   = 16384;
    const size_t cnt_bytes = (size_t)NB * R3 * 4;               // 1 MB
    const size_t off_cur   = off_cnt + cnt_bytes;
    const size_t off_vid   = off_cur + cnt_bytes;
    const size_t vid_bytes = (size_t)NB * NPTS * 4;             // 2 MB
    const size_t off_vs    = off_vid + vid_bytes;
    const size_t off_ft    = off_vs + vid_bytes;
    const size_t ft_bytes  = (size_t)NB * NPTS * NCH * 2;       // 64 MB fp16
    const size_t need_sort = off_ft + ft_bytes;                 // ~70 MB

    // fallback layout
    const size_t off_vox   = off_cnt + cnt_bytes;
    const size_t vox_bytes = (size_t)NB * R3 * NCH * 4;         // 64 MB
    const size_t need_vm   = off_vox + vox_bytes;               // ~65 MB

    if (ws_size >= need_sort) {
        unsigned* cnt    = (unsigned*)((char*)d_ws + off_cnt);
        unsigned* cursor = (unsigned*)((char*)d_ws + off_cur);
        int*      vid    = (int*)((char*)d_ws + off_vid);
        int*      vid_s  = (int*)((char*)d_ws + off_vs);
        __half*   ft     = (__half*)((char*)d_ws + off_ft);

        // only cnt needs zeroing (1 MB) — voxsum accumulates in LDS
        hipMemsetAsync((char*)d_ws + off_cnt, 0, cnt_bytes, stream);

        mean1_kernel<<<dim3(64, NB), 256, 0, stream>>>(coords, part);
        mean2_kernel<<<NB, 64, 0, stream>>>(part, meanf);
        max1_kernel <<<dim3(64, NB), 256, 0, stream>>>(coords, meanf, partmax);
        max2_kernel <<<NB, 64, 0, stream>>>(partmax, denomv);
        nc_vid_kernel<<<dim3(NPTS / 256, NB), 256, 0, stream>>>(coords, meanf, denomv,
                                                                ncout, vid, cnt);
        scan_kernel  <<<NB, 1024, 0, stream>>>(cnt, cursor);
        permute_kernel<<<dim3(NPTS / 64, NB), 256, 0, stream>>>(feats, vid, cursor, ft, vid_s);
        voxsum_kernel <<<dim3(R3 / 64, NB), 256, 0, stream>>>(ft, vid_s, cursor, cnt, voxout);
    } else if (ws_size >= need_vm) {
        float* cntf   = (float*)((char*)d_ws + off_cnt);
        float* ws_vox = (float*)((char*)d_ws + off_vox);
        hipMemsetAsync((char*)d_ws + off_cnt, 0, cnt_bytes + vox_bytes, stream);
        mean1_kernel<<<dim3(64, NB), 256, 0, stream>>>(coords, part);
        mean2_kernel<<<NB, 64, 0, stream>>>(part, meanf);
        max1_kernel <<<dim3(64, NB), 256, 0, stream>>>(coords, meanf, partmax);
        max2_kernel <<<NB, 64, 0, stream>>>(partmax, denomv);
        scatter_vm_kernel<<<dim3(NPTS / 64, NB), 256, 0, stream>>>(
            feats, coords, meanf, denomv, ws_vox, ncout, cntf);
        normalize_tf_kernel<<<dim3(R3 / 64, NB), 256, 0, stream>>>(ws_vox, cntf, voxout);
    }
}

// Round 9
// 338.450 us; speedup vs baseline: 1.3514x; 1.3514x over previous
//
#include <hip/hip_runtime.h>
#include <hip/hip_fp16.h>

#define RR 32
#define R3 32768           // 32^3
#define NPTS 65536
#define NCH 64
#define NB 8

// ---------------- atomic-free reductions ----------------

// grid (64, NB), block 256; each block reduces 1024 points -> part[(b*64+blk)*3+axis]
__global__ void mean1_kernel(const float* __restrict__ coords, double* __restrict__ part) {
    __shared__ double ls[3][4];
    int b = blockIdx.y, blk = blockIdx.x;
    int t = threadIdx.x;
    const float* cb = coords + (size_t)b * 3 * NPTS;
    int base = blk * 1024 + t;
    double sx = 0.0, sy = 0.0, sz = 0.0;
#pragma unroll
    for (int k = 0; k < 4; k++) {
        int n = base + k * 256;
        sx += cb[n];
        sy += cb[NPTS + n];
        sz += cb[2 * NPTS + n];
    }
    for (int off = 32; off > 0; off >>= 1) {
        sx += __shfl_down(sx, off);
        sy += __shfl_down(sy, off);
        sz += __shfl_down(sz, off);
    }
    int wave = t >> 6;
    if ((t & 63) == 0) { ls[0][wave] = sx; ls[1][wave] = sy; ls[2][wave] = sz; }
    __syncthreads();
    if (t == 0) {
        part[((size_t)b * 64 + blk) * 3 + 0] = ls[0][0] + ls[0][1] + ls[0][2] + ls[0][3];
        part[((size_t)b * 64 + blk) * 3 + 1] = ls[1][0] + ls[1][1] + ls[1][2] + ls[1][3];
        part[((size_t)b * 64 + blk) * 3 + 2] = ls[2][0] + ls[2][1] + ls[2][2] + ls[2][3];
    }
}

// grid NB, block 64; combine 64 partials -> meanf[b*4+axis]
__global__ void mean2_kernel(const double* __restrict__ part, float* __restrict__ meanf) {
    int b = blockIdx.x, l = threadIdx.x;
    double sx = part[((size_t)b * 64 + l) * 3 + 0];
    double sy = part[((size_t)b * 64 + l) * 3 + 1];
    double sz = part[((size_t)b * 64 + l) * 3 + 2];
    for (int off = 32; off > 0; off >>= 1) {
        sx += __shfl_down(sx, off);
        sy += __shfl_down(sy, off);
        sz += __shfl_down(sz, off);
    }
    if (l == 0) {
        meanf[b * 4 + 0] = (float)(sx * (1.0 / NPTS));
        meanf[b * 4 + 1] = (float)(sy * (1.0 / NPTS));
        meanf[b * 4 + 2] = (float)(sz * (1.0 / NPTS));
    }
}

// grid (64, NB), block 256; partial max of squared dist -> partmax[b*64+blk]
__global__ void max1_kernel(const float* __restrict__ coords,
                            const float* __restrict__ meanf,
                            float* __restrict__ partmax) {
    __shared__ float ls[4];
    int b = blockIdx.y, blk = blockIdx.x;
    int t = threadIdx.x;
    float mx = meanf[b * 4 + 0], my = meanf[b * 4 + 1], mz = meanf[b * 4 + 2];
    const float* cb = coords + (size_t)b * 3 * NPTS;
    int base = blk * 1024 + t;
    float m = 0.0f;
#pragma unroll
    for (int k = 0; k < 4; k++) {
        int n = base + k * 256;
        float dx = cb[n] - mx;
        float dy = cb[NPTS + n] - my;
        float dz = cb[2 * NPTS + n] - mz;
        m = fmaxf(m, dx * dx + dy * dy + dz * dz);
    }
    for (int off = 32; off > 0; off >>= 1) m = fmaxf(m, __shfl_down(m, off));
    int wave = t >> 6;
    if ((t & 63) == 0) ls[wave] = m;
    __syncthreads();
    if (t == 0) partmax[b * 64 + blk] = fmaxf(fmaxf(ls[0], ls[1]), fmaxf(ls[2], ls[3]));
}

// grid NB, block 64; combine -> denom[b] = 2*sqrt(max)
__global__ void max2_kernel(const float* __restrict__ partmax, float* __restrict__ denom) {
    int b = blockIdx.x, l = threadIdx.x;
    float m = partmax[b * 64 + l];
    for (int off = 32; off > 0; off >>= 1) m = fmaxf(m, __shfl_down(m, off));
    if (l == 0) denom[b] = 2.0f * sqrtf(m);   // EPS = 0
}

// ---------------- sorted pipeline ----------------

__global__ void nc_vid_kernel(const float* __restrict__ coords,
                              const float* __restrict__ meanf,
                              const float* __restrict__ denomv,
                              float* __restrict__ ncout,
                              int* __restrict__ vid,
                              unsigned* __restrict__ cnt) {
    int b = blockIdx.y;
    int n = blockIdx.x * blockDim.x + threadIdx.x;
    float mx = meanf[b * 4 + 0], my = meanf[b * 4 + 1], mz = meanf[b * 4 + 2];
    float denom = denomv[b];
    const float* cb = coords + (size_t)b * 3 * NPTS;
    float dx = cb[n] - mx;
    float dy = cb[NPTS + n] - my;
    float dz = cb[2 * NPTS + n] - mz;
    float qx = fminf(fmaxf((dx / denom + 0.5f) * 32.0f, 0.0f), 31.0f);
    float qy = fminf(fmaxf((dy / denom + 0.5f) * 32.0f, 0.0f), 31.0f);
    float qz = fminf(fmaxf((dz / denom + 0.5f) * 32.0f, 0.0f), 31.0f);
    float* nb_ = ncout + (size_t)b * 3 * NPTS;
    nb_[n] = qx;
    nb_[NPTS + n] = qy;
    nb_[2 * NPTS + n] = qz;
    int flat = ((int)rintf(qx) * RR + (int)rintf(qy)) * RR + (int)rintf(qz);
    vid[b * NPTS + n] = flat;
    atomicAdd(&cnt[b * R3 + flat], 1u);
}

// ---- 3-phase parallel scan (replaces 8-block scan: was 3% CU utilization) ----
// scan1: grid (32, NB) x 256; block-local exclusive prefix over 1024 voxels.
__global__ void scan1_kernel(const unsigned* __restrict__ cnt,
                             unsigned* __restrict__ cursor,
                             unsigned* __restrict__ tot) {
    __shared__ unsigned ls[256];
    int b = blockIdx.y, blk = blockIdx.x, t = threadIdx.x;
    const unsigned* c = cnt + b * R3 + blk * 1024;
    uint4 v = *reinterpret_cast<const uint4*>(c + t * 4);
    unsigned s = v.x + v.y + v.z + v.w;
    ls[t] = s;
    __syncthreads();
    for (int d = 1; d < 256; d <<= 1) {
        unsigned x = (t >= d) ? ls[t - d] : 0u;
        __syncthreads();
        ls[t] += x;
        __syncthreads();
    }
    unsigned base = (t == 0) ? 0u : ls[t - 1];
    if (t == 255) tot[b * 32 + blk] = ls[255];
    uint4 o;
    o.x = base;
    o.y = base + v.x;
    o.z = base + v.x + v.y;
    o.w = base + v.x + v.y + v.z;
    *reinterpret_cast<uint4*>(cursor + b * R3 + blk * 1024 + t * 4) = o;
}

// scan2: 1 block x 512; wave w scans batch w's 32 block-totals -> exclusive.
__global__ void scan2_kernel(unsigned* __restrict__ tot) {
    int b = threadIdx.x >> 6;
    int lane = threadIdx.x & 63;
    unsigned v = (lane < 32) ? tot[b * 32 + lane] : 0u;
    unsigned orig = v;
    for (int d = 1; d < 32; d <<= 1) {
        unsigned x = __shfl_up(v, d);
        if (lane >= d && lane < 32) v += x;
    }
    if (lane < 32) tot[b * 32 + lane] = v - orig;   // exclusive
}

// scan3: grid (32, NB) x 256; add per-block offsets.
__global__ void scan3_kernel(unsigned* __restrict__ cursor,
                             const unsigned* __restrict__ tot) {
    int b = blockIdx.y, blk = blockIdx.x, t = threadIdx.x;
    unsigned off = tot[b * 32 + blk];
    uint4* p = reinterpret_cast<uint4*>(cursor + b * R3 + blk * 1024 + t * 4);
    uint4 v = *p;
    v.x += off; v.y += off; v.z += off; v.w += off;
    *p = v;
}

// Transpose 64x64 feature tile AND scatter rows to sorted positions (fp16).
// Scattered ft stores are NONTEMPORAL: each wave-store is a full aligned
// 128B line (32 lanes x half2), so streaming stores skip the write-allocate
// fetch (R5 showed FETCH 67MB despite L3-warm feats -> RFO suspected).
__global__ void permute_kernel(const float* __restrict__ feats,
                               const int* __restrict__ vid,
                               unsigned* __restrict__ cursor,
                               __half* __restrict__ ft,
                               int* __restrict__ vid_sorted) {
    __shared__ float tile[64][65];
    __shared__ int spos[64];
    int b  = blockIdx.y;
    int n0 = blockIdx.x * 64;
    int t  = threadIdx.x;

    if (t < 64) {
        int flat = vid[b * NPTS + n0 + t];
        int pos = (int)atomicAdd(&cursor[b * R3 + flat], 1u);
        spos[t] = pos;
        vid_sorted[b * NPTS + pos] = flat;
    }

    const float* fb = feats + (size_t)b * NCH * NPTS + n0;
    int i  = t & 63;
    int c0w = t >> 6;
#pragma unroll
    for (int iter = 0; iter < 16; iter++) {
        int c = iter * 4 + c0w;
        tile[i][c] = fb[(size_t)c * NPTS + i];
    }
    __syncthreads();

    int wave = t >> 6;
    int lane = t & 63;
    int hp = lane >> 5;              // which point of the pair
    int c0 = (lane & 31) * 2;        // channel pair
    __half* fbase = ft + (size_t)b * NPTS * NCH;
#pragma unroll
    for (int j = 0; j < 8; j++) {
        int p = wave * 16 + j * 2 + hp;
        __half2 hv = __floats2half2_rn(tile[p][c0], tile[p][c0 + 1]);
        unsigned u = *reinterpret_cast<unsigned*>(&hv);
        __builtin_nontemporal_store(
            u, reinterpret_cast<unsigned*>(fbase + (size_t)spos[p] * NCH + c0));
    }
}

// Balanced segmented sum: each half-wave owns 32 consecutive sorted
// positions; each lane covers a channel PAIR (half2 loads, 128B contiguous
// per half-wave per position). Run partials flushed via atomicAdd into
// zero-initialized ws_vox.
__global__ void segsum_kernel(const __half* __restrict__ ft,
                              const int* __restrict__ vid_sorted,
                              float* __restrict__ ws_vox) {
    __shared__ int sv[257];
    int b   = blockIdx.y;
    int t   = threadIdx.x;
    int bp0 = blockIdx.x * 256;

    sv[t] = vid_sorted[b * NPTS + bp0 + t];
    if (t == 0)
        sv[256] = (bp0 + 256 < NPTS) ? vid_sorted[b * NPTS + bp0 + 256] : -1;
    __syncthreads();

    int wave  = t >> 6;
    int lane  = t & 63;
    int chunk = wave * 2 + (lane >> 5);   // 0..7, 32 positions each
    int c0    = (lane & 31) * 2;          // channel pair
    int p0    = chunk * 32;

    const __half* fb = ft + ((size_t)b * NPTS + bp0 + p0) * NCH + c0;
    float* wv = ws_vox + (size_t)b * R3 * NCH + c0;

    float sx = 0.0f, sy = 0.0f;
    int vcur = sv[p0];
#pragma unroll
    for (int k = 0; k < 32; k++) {
        __half2 h = *reinterpret_cast<const __half2*>(fb + (size_t)k * NCH);
        float2 f = __half22float2(h);
        sx += f.x;
        sy += f.y;
        int vnext = sv[p0 + k + 1];       // p0+32 valid: sv has 257 entries
        if (vnext != vcur) {
            atomicAdd(wv + (size_t)vcur * NCH, sx);
            atomicAdd(wv + (size_t)vcur * NCH + 1, sy);
            sx = 0.0f;
            sy = 0.0f;
            vcur = vnext;
        }
    }
    if (sx != 0.0f || sy != 0.0f) {       // tail partial (adds 0 if none)
        atomicAdd(wv + (size_t)vcur * NCH, sx);
        atomicAdd(wv + (size_t)vcur * NCH + 1, sy);
    }
}

// ws_vox [B][R3][C] -> voxout [B][C][R3], divide by count, skip empty voxels.
__global__ void normalize_t_kernel(const float* __restrict__ ws_vox,
                                   const unsigned* __restrict__ cnt,
                                   float* __restrict__ voxout) {
    __shared__ float tile[64][65];
    __shared__ float cinv[64];
    __shared__ unsigned scnt[64];
    int b  = blockIdx.y;
    int v0 = blockIdx.x * 64;
    int t  = threadIdx.x;
    if (t < 64) {
        unsigned c = cnt[b * R3 + v0 + t];
        scnt[t] = c;
        cinv[t] = 1.0f / fmaxf((float)c, 1.0f);
    }
    __syncthreads();
    const float* src = ws_vox + ((size_t)b * R3 + v0) * NCH;
    int c = t & 63;
    int w = t >> 6;
#pragma unroll
    for (int iter = 0; iter < 16; iter++) {
        int vi = iter * 4 + w;
        tile[c][vi] = scnt[vi] ? src[(size_t)vi * NCH + c] * cinv[vi] : 0.0f;
    }
    __syncthreads();
    float* dst = voxout + (size_t)b * NCH * R3 + v0;
    int vi = t & 63;
#pragma unroll
    for (int iter = 0; iter < 16; iter++) {
        int cc = iter * 4 + w;
        dst[(size_t)cc * R3 + vi] = tile[cc][vi];
    }
}

// ---------------- fallback: voxel-major atomics ----------------

__global__ void scatter_vm_kernel(const float* __restrict__ feats,
                                  const float* __restrict__ coords,
                                  const float* __restrict__ meanf,
                                  const float* __restrict__ denomv,
                                  float* __restrict__ ws_vox,
                                  float* __restrict__ ncout,
                                  float* __restrict__ cnt) {
    __shared__ float tile[64][65];
    __shared__ int   sflat[64];
    int b  = blockIdx.y;
    int n0 = blockIdx.x * 64;
    int t  = threadIdx.x;
    if (t < 64) {
        int n = n0 + t;
        float mx = meanf[b * 4 + 0], my = meanf[b * 4 + 1], mz = meanf[b * 4 + 2];
        float denom = denomv[b];
        const float* cb = coords + (size_t)b * 3 * NPTS;
        float dx = cb[n] - mx;
        float dy = cb[NPTS + n] - my;
        float dz = cb[2 * NPTS + n] - mz;
        float qx = fminf(fmaxf((dx / denom + 0.5f) * 32.0f, 0.0f), 31.0f);
        float qy = fminf(fmaxf((dy / denom + 0.5f) * 32.0f, 0.0f), 31.0f);
        float qz = fminf(fmaxf((dz / denom + 0.5f) * 32.0f, 0.0f), 31.0f);
        float* nb_ = ncout + (size_t)b * 3 * NPTS;
        nb_[n] = qx;
        nb_[NPTS + n] = qy;
        nb_[2 * NPTS + n] = qz;
        int flat = ((int)rintf(qx) * RR + (int)rintf(qy)) * RR + (int)rintf(qz);
        sflat[t] = flat;
        atomicAdd(&cnt[b * R3 + flat], 1.0f);
    }
    const float* fb = feats + (size_t)b * NCH * NPTS + n0;
    int i = t & 63;
    int c0 = t >> 6;
#pragma unroll
    for (int iter = 0; iter < 16; iter++) {
        int c = iter * 4 + c0;
        tile[i][c] = fb[(size_t)c * NPTS + i];
    }
    __syncthreads();
    int wave = t >> 6;
    int lane = t & 63;
#pragma unroll
    for (int k = 0; k < 16; k++) {
        int p = wave * 16 + k;
        float v = tile[p][lane];
        size_t base = ((size_t)b * R3 + sflat[p]) * NCH;
        atomicAdd(&ws_vox[base + lane], v);
    }
}

__global__ void normalize_tf_kernel(const float* __restrict__ ws_vox,
                                    const float* __restrict__ cnt,
                                    float* __restrict__ voxout) {
    __shared__ float tile[64][65];
    __shared__ float cinv[64];
    int b  = blockIdx.y;
    int v0 = blockIdx.x * 64;
    int t  = threadIdx.x;
    if (t < 64) cinv[t] = 1.0f / fmaxf(cnt[b * R3 + v0 + t], 1.0f);
    __syncthreads();
    const float* src = ws_vox + ((size_t)b * R3 + v0) * NCH;
    int c = t & 63;
    int w = t >> 6;
#pragma unroll
    for (int iter = 0; iter < 16; iter++) {
        int vi = iter * 4 + w;
        tile[c][vi] = src[(size_t)vi * NCH + c] * cinv[vi];
    }
    __syncthreads();
    float* dst = voxout + (size_t)b * NCH * R3 + v0;
    int vi = t & 63;
#pragma unroll
    for (int iter = 0; iter < 16; iter++) {
        int cc = iter * 4 + w;
        dst[(size_t)cc * R3 + vi] = tile[cc][vi];
    }
}

extern "C" void kernel_launch(void* const* d_in, const int* in_sizes, int n_in,
                              void* d_out, int out_size, void* d_ws, size_t ws_size,
                              hipStream_t stream) {
    const float* feats  = (const float*)d_in[0];   // [8,64,65536]
    const float* coords = (const float*)d_in[1];   // [8,3,65536]
    float* out = (float*)d_out;
    float* voxout = out;                                   // [8,64,32768]
    float* ncout  = out + (size_t)NB * NCH * R3;           // [8,3,65536]

    // small scratch (no zeroing needed — all plain-written before read)
    double* part    = (double*)d_ws;                               // [NB*64*3] = 12 KB
    float*  partmax = (float*)((char*)d_ws + 12544);               // [NB*64]   = 2 KB
    float*  meanf   = (float*)((char*)d_ws + 14592);               // [NB*4]
    float*  denomv  = (float*)((char*)d_ws + 14720);               // [NB]
    unsigned* tot   = (unsigned*)((char*)d_ws + 14848);            // [NB*32] = 1 KB

    const size_t off_cnt   = 16384;
    const size_t cnt_bytes = (size_t)NB * R3 * 4;               // 1 MB
    const size_t off_vox   = off_cnt + cnt_bytes;
    const size_t vox_bytes = (size_t)NB * R3 * NCH * 4;         // 64 MB
    const size_t off_cur   = off_vox + vox_bytes;
    const size_t off_vid   = off_cur + cnt_bytes;
    const size_t vid_bytes = (size_t)NB * NPTS * 4;             // 2 MB
    const size_t off_vs    = off_vid + vid_bytes;
    const size_t off_ft    = off_vs + vid_bytes;
    const size_t ft_bytes  = (size_t)NB * NPTS * NCH * 2;       // 64 MB fp16
    const size_t need_sort = off_ft + ft_bytes;                 // ~135 MB
    const size_t need_vm   = off_vox + vox_bytes;               // ~65 MB

    if (ws_size >= need_sort) {
        unsigned* cnt    = (unsigned*)((char*)d_ws + off_cnt);
        float*    ws_vox = (float*)((char*)d_ws + off_vox);
        unsigned* cursor = (unsigned*)((char*)d_ws + off_cur);
        int*      vid    = (int*)((char*)d_ws + off_vid);
        int*      vid_s  = (int*)((char*)d_ws + off_vs);
        __half*   ft     = (__half*)((char*)d_ws + off_ft);

        // atomic segsum needs cnt AND ws_vox zeroed (contiguous region)
        hipMemsetAsync((char*)d_ws + off_cnt, 0, cnt_bytes + vox_bytes, stream);

        mean1_kernel<<<dim3(64, NB), 256, 0, stream>>>(coords, part);
        mean2_kernel<<<NB, 64, 0, stream>>>(part, meanf);
        max1_kernel <<<dim3(64, NB), 256, 0, stream>>>(coords, meanf, partmax);
        max2_kernel <<<NB, 64, 0, stream>>>(partmax, denomv);
        nc_vid_kernel<<<dim3(NPTS / 256, NB), 256, 0, stream>>>(coords, meanf, denomv,
                                                                ncout, vid, cnt);
        scan1_kernel<<<dim3(32, NB), 256, 0, stream>>>(cnt, cursor, tot);
        scan2_kernel<<<1, 512, 0, stream>>>(tot);
        scan3_kernel<<<dim3(32, NB), 256, 0, stream>>>(cursor, tot);
        permute_kernel<<<dim3(NPTS / 64, NB), 256, 0, stream>>>(feats, vid, cursor, ft, vid_s);
        segsum_kernel <<<dim3(NPTS / 256, NB), 256, 0, stream>>>(ft, vid_s, ws_vox);
        normalize_t_kernel<<<dim3(R3 / 64, NB), 256, 0, stream>>>(ws_vox, cnt, voxout);
    } else if (ws_size >= need_vm) {
        float* cntf   = (float*)((char*)d_ws + off_cnt);
        float* ws_vox = (float*)((char*)d_ws + off_vox);
        hipMemsetAsync((char*)d_ws + off_cnt, 0, cnt_bytes + vox_bytes, stream);
        mean1_kernel<<<dim3(64, NB), 256, 0, stream>>>(coords, part);
        mean2_kernel<<<NB, 64, 0, stream>>>(part, meanf);
        max1_kernel <<<dim3(64, NB), 256, 0, stream>>>(coords, meanf, partmax);
        max2_kernel <<<NB, 64, 0, stream>>>(partmax, denomv);
        scatter_vm_kernel<<<dim3(NPTS / 64, NB), 256, 0, stream>>>(
            feats, coords, meanf, denomv, ws_vox, ncout, cntf);
        normalize_tf_kernel<<<dim3(R3 / 64, NB), 256, 0, stream>>>(ws_vox, cntf, voxout);
    }
}

// Round 10
// 324.444 us; speedup vs baseline: 1.4097x; 1.0432x over previous
//
#include <hip/hip_runtime.h>
#include <hip/hip_fp16.h>

#define RR 32
#define R3 32768           // 32^3
#define NPTS 65536
#define NCH 64
#define NB 8

// ---------------- atomic-free reductions ----------------

// grid (64, NB), block 256; each block reduces 1024 points -> part[(b*64+blk)*3+axis]
__global__ void mean1_kernel(const float* __restrict__ coords, double* __restrict__ part) {
    __shared__ double ls[3][4];
    int b = blockIdx.y, blk = blockIdx.x;
    int t = threadIdx.x;
    const float* cb = coords + (size_t)b * 3 * NPTS;
    int base = blk * 1024 + t;
    double sx = 0.0, sy = 0.0, sz = 0.0;
#pragma unroll
    for (int k = 0; k < 4; k++) {
        int n = base + k * 256;
        sx += cb[n];
        sy += cb[NPTS + n];
        sz += cb[2 * NPTS + n];
    }
    for (int off = 32; off > 0; off >>= 1) {
        sx += __shfl_down(sx, off);
        sy += __shfl_down(sy, off);
        sz += __shfl_down(sz, off);
    }
    int wave = t >> 6;
    if ((t & 63) == 0) { ls[0][wave] = sx; ls[1][wave] = sy; ls[2][wave] = sz; }
    __syncthreads();
    if (t == 0) {
        part[((size_t)b * 64 + blk) * 3 + 0] = ls[0][0] + ls[0][1] + ls[0][2] + ls[0][3];
        part[((size_t)b * 64 + blk) * 3 + 1] = ls[1][0] + ls[1][1] + ls[1][2] + ls[1][3];
        part[((size_t)b * 64 + blk) * 3 + 2] = ls[2][0] + ls[2][1] + ls[2][2] + ls[2][3];
    }
}

// grid NB, block 64; combine 64 partials -> meanf[b*4+axis]
__global__ void mean2_kernel(const double* __restrict__ part, float* __restrict__ meanf) {
    int b = blockIdx.x, l = threadIdx.x;
    double sx = part[((size_t)b * 64 + l) * 3 + 0];
    double sy = part[((size_t)b * 64 + l) * 3 + 1];
    double sz = part[((size_t)b * 64 + l) * 3 + 2];
    for (int off = 32; off > 0; off >>= 1) {
        sx += __shfl_down(sx, off);
        sy += __shfl_down(sy, off);
        sz += __shfl_down(sz, off);
    }
    if (l == 0) {
        meanf[b * 4 + 0] = (float)(sx * (1.0 / NPTS));
        meanf[b * 4 + 1] = (float)(sy * (1.0 / NPTS));
        meanf[b * 4 + 2] = (float)(sz * (1.0 / NPTS));
    }
}

// grid (64, NB), block 256; partial max of squared dist -> partmax[b*64+blk]
__global__ void max1_kernel(const float* __restrict__ coords,
                            const float* __restrict__ meanf,
                            float* __restrict__ partmax) {
    __shared__ float ls[4];
    int b = blockIdx.y, blk = blockIdx.x;
    int t = threadIdx.x;
    float mx = meanf[b * 4 + 0], my = meanf[b * 4 + 1], mz = meanf[b * 4 + 2];
    const float* cb = coords + (size_t)b * 3 * NPTS;
    int base = blk * 1024 + t;
    float m = 0.0f;
#pragma unroll
    for (int k = 0; k < 4; k++) {
        int n = base + k * 256;
        float dx = cb[n] - mx;
        float dy = cb[NPTS + n] - my;
        float dz = cb[2 * NPTS + n] - mz;
        m = fmaxf(m, dx * dx + dy * dy + dz * dz);
    }
    for (int off = 32; off > 0; off >>= 1) m = fmaxf(m, __shfl_down(m, off));
    int wave = t >> 6;
    if ((t & 63) == 0) ls[wave] = m;
    __syncthreads();
    if (t == 0) partmax[b * 64 + blk] = fmaxf(fmaxf(ls[0], ls[1]), fmaxf(ls[2], ls[3]));
}

// grid NB, block 64; combine -> denom[b] = 2*sqrt(max)
__global__ void max2_kernel(const float* __restrict__ partmax, float* __restrict__ denom) {
    int b = blockIdx.x, l = threadIdx.x;
    float m = partmax[b * 64 + l];
    for (int off = 32; off > 0; off >>= 1) m = fmaxf(m, __shfl_down(m, off));
    if (l == 0) denom[b] = 2.0f * sqrtf(m);   // EPS = 0
}

// ---------------- sorted pipeline ----------------

// 4 points per thread, float4 IO. grid (NPTS/1024, NB) x 256.
__global__ void nc_vid_kernel(const float* __restrict__ coords,
                              const float* __restrict__ meanf,
                              const float* __restrict__ denomv,
                              float* __restrict__ ncout,
                              int* __restrict__ vid,
                              unsigned* __restrict__ cnt) {
    int b = blockIdx.y;
    int n0 = (blockIdx.x * 256 + threadIdx.x) * 4;
    float mx = meanf[b * 4 + 0], my = meanf[b * 4 + 1], mz = meanf[b * 4 + 2];
    float rden = 32.0f / denomv[b];
    const float* cb = coords + (size_t)b * 3 * NPTS;
    float4 x4 = *reinterpret_cast<const float4*>(cb + n0);
    float4 y4 = *reinterpret_cast<const float4*>(cb + NPTS + n0);
    float4 z4 = *reinterpret_cast<const float4*>(cb + 2 * NPTS + n0);
    float qx[4], qy[4], qz[4];
    qx[0] = fminf(fmaxf((x4.x - mx) * rden + 16.0f, 0.0f), 31.0f);
    qx[1] = fminf(fmaxf((x4.y - mx) * rden + 16.0f, 0.0f), 31.0f);
    qx[2] = fminf(fmaxf((x4.z - mx) * rden + 16.0f, 0.0f), 31.0f);
    qx[3] = fminf(fmaxf((x4.w - mx) * rden + 16.0f, 0.0f), 31.0f);
    qy[0] = fminf(fmaxf((y4.x - my) * rden + 16.0f, 0.0f), 31.0f);
    qy[1] = fminf(fmaxf((y4.y - my) * rden + 16.0f, 0.0f), 31.0f);
    qy[2] = fminf(fmaxf((y4.z - my) * rden + 16.0f, 0.0f), 31.0f);
    qy[3] = fminf(fmaxf((y4.w - my) * rden + 16.0f, 0.0f), 31.0f);
    qz[0] = fminf(fmaxf((z4.x - mz) * rden + 16.0f, 0.0f), 31.0f);
    qz[1] = fminf(fmaxf((z4.y - mz) * rden + 16.0f, 0.0f), 31.0f);
    qz[2] = fminf(fmaxf((z4.z - mz) * rden + 16.0f, 0.0f), 31.0f);
    qz[3] = fminf(fmaxf((z4.w - mz) * rden + 16.0f, 0.0f), 31.0f);
    float* nb_ = ncout + (size_t)b * 3 * NPTS;
    *reinterpret_cast<float4*>(nb_ + n0)             = make_float4(qx[0], qx[1], qx[2], qx[3]);
    *reinterpret_cast<float4*>(nb_ + NPTS + n0)      = make_float4(qy[0], qy[1], qy[2], qy[3]);
    *reinterpret_cast<float4*>(nb_ + 2 * NPTS + n0)  = make_float4(qz[0], qz[1], qz[2], qz[3]);
    int fl[4];
#pragma unroll
    for (int k = 0; k < 4; k++) {
        fl[k] = ((int)rintf(qx[k]) * RR + (int)rintf(qy[k])) * RR + (int)rintf(qz[k]);
        atomicAdd(&cnt[b * R3 + fl[k]], 1u);
    }
    *reinterpret_cast<int4*>(vid + b * NPTS + n0) = make_int4(fl[0], fl[1], fl[2], fl[3]);
}

// ---- 3-phase parallel scan ----
// scan1: grid (32, NB) x 256; block-local exclusive prefix over 1024 voxels.
__global__ void scan1_kernel(const unsigned* __restrict__ cnt,
                             unsigned* __restrict__ cursor,
                             unsigned* __restrict__ tot) {
    __shared__ unsigned ls[256];
    int b = blockIdx.y, blk = blockIdx.x, t = threadIdx.x;
    const unsigned* c = cnt + b * R3 + blk * 1024;
    uint4 v = *reinterpret_cast<const uint4*>(c + t * 4);
    unsigned s = v.x + v.y + v.z + v.w;
    ls[t] = s;
    __syncthreads();
    for (int d = 1; d < 256; d <<= 1) {
        unsigned x = (t >= d) ? ls[t - d] : 0u;
        __syncthreads();
        ls[t] += x;
        __syncthreads();
    }
    unsigned base = (t == 0) ? 0u : ls[t - 1];
    if (t == 255) tot[b * 32 + blk] = ls[255];
    uint4 o;
    o.x = base;
    o.y = base + v.x;
    o.z = base + v.x + v.y;
    o.w = base + v.x + v.y + v.z;
    *reinterpret_cast<uint4*>(cursor + b * R3 + blk * 1024 + t * 4) = o;
}

// scan2: 1 block x 512; wave w scans batch w's 32 block-totals -> exclusive.
__global__ void scan2_kernel(unsigned* __restrict__ tot) {
    int b = threadIdx.x >> 6;
    int lane = threadIdx.x & 63;
    unsigned v = (lane < 32) ? tot[b * 32 + lane] : 0u;
    unsigned orig = v;
    for (int d = 1; d < 32; d <<= 1) {
        unsigned x = __shfl_up(v, d);
        if (lane >= d && lane < 32) v += x;
    }
    if (lane < 32) tot[b * 32 + lane] = v - orig;   // exclusive
}

// scan3: grid (32, NB) x 256; add per-block offsets.
__global__ void scan3_kernel(unsigned* __restrict__ cursor,
                             const unsigned* __restrict__ tot) {
    int b = blockIdx.y, blk = blockIdx.x, t = threadIdx.x;
    unsigned off = tot[b * 32 + blk];
    uint4* p = reinterpret_cast<uint4*>(cursor + b * R3 + blk * 1024 + t * 4);
    uint4 v = *p;
    v.x += off; v.y += off; v.z += off; v.w += off;
    *p = v;
}

// Transpose 64x64 feature tile AND scatter rows to sorted positions (fp16).
// Scattered ft stores are NONTEMPORAL full 128B lines (no write-allocate).
__global__ void permute_kernel(const float* __restrict__ feats,
                               const int* __restrict__ vid,
                               unsigned* __restrict__ cursor,
                               __half* __restrict__ ft,
                               int* __restrict__ vid_sorted) {
    __shared__ float tile[64][65];
    __shared__ int spos[64];
    int b  = blockIdx.y;
    int n0 = blockIdx.x * 64;
    int t  = threadIdx.x;

    if (t < 64) {
        int flat = vid[b * NPTS + n0 + t];
        int pos = (int)atomicAdd(&cursor[b * R3 + flat], 1u);
        spos[t] = pos;
        vid_sorted[b * NPTS + pos] = flat;
    }

    const float* fb = feats + (size_t)b * NCH * NPTS + n0;
    int i  = t & 63;
    int c0w = t >> 6;
#pragma unroll
    for (int iter = 0; iter < 16; iter++) {
        int c = iter * 4 + c0w;
        tile[i][c] = fb[(size_t)c * NPTS + i];
    }
    __syncthreads();

    int wave = t >> 6;
    int lane = t & 63;
    int hp = lane >> 5;              // which point of the pair
    int c0 = (lane & 31) * 2;        // channel pair
    __half* fbase = ft + (size_t)b * NPTS * NCH;
#pragma unroll
    for (int j = 0; j < 8; j++) {
        int p = wave * 16 + j * 2 + hp;
        __half2 hv = __floats2half2_rn(tile[p][c0], tile[p][c0 + 1]);
        unsigned u = *reinterpret_cast<unsigned*>(&hv);
        __builtin_nontemporal_store(
            u, reinterpret_cast<unsigned*>(fbase + (size_t)spos[p] * NCH + c0));
    }
}

// Balanced segmented sum: each half-wave owns 32 consecutive sorted
// positions; each lane covers a channel PAIR. ft loads nontemporal
// (stream-once; keep L2 for ws_vox atomic lines). Run partials flushed
// via atomicAdd into zero-initialized ws_vox.
__global__ void segsum_kernel(const __half* __restrict__ ft,
                              const int* __restrict__ vid_sorted,
                              float* __restrict__ ws_vox) {
    __shared__ int sv[257];
    int b   = blockIdx.y;
    int t   = threadIdx.x;
    int bp0 = blockIdx.x * 256;

    sv[t] = vid_sorted[b * NPTS + bp0 + t];
    if (t == 0)
        sv[256] = (bp0 + 256 < NPTS) ? vid_sorted[b * NPTS + bp0 + 256] : -1;
    __syncthreads();

    int wave  = t >> 6;
    int lane  = t & 63;
    int chunk = wave * 2 + (lane >> 5);   // 0..7, 32 positions each
    int c0    = (lane & 31) * 2;          // channel pair
    int p0    = chunk * 32;

    const __half* fb = ft + ((size_t)b * NPTS + bp0 + p0) * NCH + c0;
    float* wv = ws_vox + (size_t)b * R3 * NCH + c0;

    float sx = 0.0f, sy = 0.0f;
    int vcur = sv[p0];
#pragma unroll
    for (int k = 0; k < 32; k++) {
        unsigned u = __builtin_nontemporal_load(
            reinterpret_cast<const unsigned*>(fb + (size_t)k * NCH));
        __half2 h = *reinterpret_cast<__half2*>(&u);
        float2 f = __half22float2(h);
        sx += f.x;
        sy += f.y;
        int vnext = sv[p0 + k + 1];       // p0+32 valid: sv has 257 entries
        if (vnext != vcur) {
            atomicAdd(wv + (size_t)vcur * NCH, sx);
            atomicAdd(wv + (size_t)vcur * NCH + 1, sy);
            sx = 0.0f;
            sy = 0.0f;
            vcur = vnext;
        }
    }
    if (sx != 0.0f || sy != 0.0f) {       // tail partial (adds 0 if none)
        atomicAdd(wv + (size_t)vcur * NCH, sx);
        atomicAdd(wv + (size_t)vcur * NCH + 1, sy);
    }
}

// ws_vox [B][R3][C] -> voxout [B][C][R3], divide by count, skip empty voxels.
// float4 both phases: read 4 channels/lane, write 4 voxels/lane.
__global__ void normalize_t_kernel(const float* __restrict__ ws_vox,
                                   const unsigned* __restrict__ cnt,
                                   float* __restrict__ voxout) {
    __shared__ float tile[64][65];    // [c][vi], skewed
    int b  = blockIdx.y;
    int v0 = blockIdx.x * 64;
    int t  = threadIdx.x;
    __shared__ float cinv[64];
    __shared__ unsigned scnt[64];
    if (t < 64) {
        unsigned c = cnt[b * R3 + v0 + t];
        scnt[t] = c;
        cinv[t] = 1.0f / fmaxf((float)c, 1.0f);
    }
    __syncthreads();
    const float* src = ws_vox + ((size_t)b * R3 + v0) * NCH;
#pragma unroll
    for (int iter = 0; iter < 4; iter++) {
        int f4 = iter * 256 + t;          // 1024 float4s total
        int vi = f4 >> 4;                 // voxel
        int c4 = (f4 & 15) * 4;           // channel quad
        float4 v;
        if (scnt[vi]) {
            v = *reinterpret_cast<const float4*>(src + (size_t)vi * NCH + c4);
            float ci = cinv[vi];
            v.x *= ci; v.y *= ci; v.z *= ci; v.w *= ci;
        } else {
            v = make_float4(0.0f, 0.0f, 0.0f, 0.0f);
        }
        tile[c4][vi] = v.x;
        tile[c4 + 1][vi] = v.y;
        tile[c4 + 2][vi] = v.z;
        tile[c4 + 3][vi] = v.w;
    }
    __syncthreads();
    float* dst = voxout + (size_t)b * NCH * R3 + v0;
#pragma unroll
    for (int iter = 0; iter < 4; iter++) {
        int f4 = iter * 256 + t;
        int c  = f4 >> 4;                 // channel
        int v4 = (f4 & 15) * 4;           // voxel quad
        float4 o = make_float4(tile[c][v4], tile[c][v4 + 1],
                               tile[c][v4 + 2], tile[c][v4 + 3]);
        *reinterpret_cast<float4*>(dst + (size_t)c * R3 + v4) = o;
    }
}

// ---------------- fallback: voxel-major atomics ----------------

__global__ void scatter_vm_kernel(const float* __restrict__ feats,
                                  const float* __restrict__ coords,
                                  const float* __restrict__ meanf,
                                  const float* __restrict__ denomv,
                                  float* __restrict__ ws_vox,
                                  float* __restrict__ ncout,
                                  float* __restrict__ cnt) {
    __shared__ float tile[64][65];
    __shared__ int   sflat[64];
    int b  = blockIdx.y;
    int n0 = blockIdx.x * 64;
    int t  = threadIdx.x;
    if (t < 64) {
        int n = n0 + t;
        float mx = meanf[b * 4 + 0], my = meanf[b * 4 + 1], mz = meanf[b * 4 + 2];
        float denom = denomv[b];
        const float* cb = coords + (size_t)b * 3 * NPTS;
        float dx = cb[n] - mx;
        float dy = cb[NPTS + n] - my;
        float dz = cb[2 * NPTS + n] - mz;
        float qx = fminf(fmaxf((dx / denom + 0.5f) * 32.0f, 0.0f), 31.0f);
        float qy = fminf(fmaxf((dy / denom + 0.5f) * 32.0f, 0.0f), 31.0f);
        float qz = fminf(fmaxf((dz / denom + 0.5f) * 32.0f, 0.0f), 31.0f);
        float* nb_ = ncout + (size_t)b * 3 * NPTS;
        nb_[n] = qx;
        nb_[NPTS + n] = qy;
        nb_[2 * NPTS + n] = qz;
        int flat = ((int)rintf(qx) * RR + (int)rintf(qy)) * RR + (int)rintf(qz);
        sflat[t] = flat;
        atomicAdd(&cnt[b * R3 + flat], 1.0f);
    }
    const float* fb = feats + (size_t)b * NCH * NPTS + n0;
    int i = t & 63;
    int c0 = t >> 6;
#pragma unroll
    for (int iter = 0; iter < 16; iter++) {
        int c = iter * 4 + c0;
        tile[i][c] = fb[(size_t)c * NPTS + i];
    }
    __syncthreads();
    int wave = t >> 6;
    int lane = t & 63;
#pragma unroll
    for (int k = 0; k < 16; k++) {
        int p = wave * 16 + k;
        float v = tile[p][lane];
        size_t base = ((size_t)b * R3 + sflat[p]) * NCH;
        atomicAdd(&ws_vox[base + lane], v);
    }
}

__global__ void normalize_tf_kernel(const float* __restrict__ ws_vox,
                                    const float* __restrict__ cnt,
                                    float* __restrict__ voxout) {
    __shared__ float tile[64][65];
    __shared__ float cinv[64];
    int b  = blockIdx.y;
    int v0 = blockIdx.x * 64;
    int t  = threadIdx.x;
    if (t < 64) cinv[t] = 1.0f / fmaxf(cnt[b * R3 + v0 + t], 1.0f);
    __syncthreads();
    const float* src = ws_vox + ((size_t)b * R3 + v0) * NCH;
    int c = t & 63;
    int w = t >> 6;
#pragma unroll
    for (int iter = 0; iter < 16; iter++) {
        int vi = iter * 4 + w;
        tile[c][vi] = src[(size_t)vi * NCH + c] * cinv[vi];
    }
    __syncthreads();
    float* dst = voxout + (size_t)b * NCH * R3 + v0;
    int vi = t & 63;
#pragma unroll
    for (int iter = 0; iter < 16; iter++) {
        int cc = iter * 4 + w;
        dst[(size_t)cc * R3 + vi] = tile[cc][vi];
    }
}

extern "C" void kernel_launch(void* const* d_in, const int* in_sizes, int n_in,
                              void* d_out, int out_size, void* d_ws, size_t ws_size,
                              hipStream_t stream) {
    const float* feats  = (const float*)d_in[0];   // [8,64,65536]
    const float* coords = (const float*)d_in[1];   // [8,3,65536]
    float* out = (float*)d_out;
    float* voxout = out;                                   // [8,64,32768]
    float* ncout  = out + (size_t)NB * NCH * R3;           // [8,3,65536]

    // small scratch (no zeroing needed — all plain-written before read)
    double* part    = (double*)d_ws;                               // [NB*64*3] = 12 KB
    float*  partmax = (float*)((char*)d_ws + 12544);               // [NB*64]   = 2 KB
    float*  meanf   = (float*)((char*)d_ws + 14592);               // [NB*4]
    float*  denomv  = (float*)((char*)d_ws + 14720);               // [NB]
    unsigned* tot   = (unsigned*)((char*)d_ws + 14848);            // [NB*32] = 1 KB

    const size_t off_cnt   = 16384;
    const size_t cnt_bytes = (size_t)NB * R3 * 4;               // 1 MB
    const size_t off_vox   = off_cnt + cnt_bytes;
    const size_t vox_bytes = (size_t)NB * R3 * NCH * 4;         // 64 MB
    const size_t off_cur   = off_vox + vox_bytes;
    const size_t off_vid   = off_cur + cnt_bytes;
    const size_t vid_bytes = (size_t)NB * NPTS * 4;             // 2 MB
    const size_t off_vs    = off_vid + vid_bytes;
    const size_t off_ft    = off_vs + vid_bytes;
    const size_t ft_bytes  = (size_t)NB * NPTS * NCH * 2;       // 64 MB fp16
    const size_t need_sort = off_ft + ft_bytes;                 // ~135 MB
    const size_t need_vm   = off_vox + vox_bytes;               // ~65 MB

    if (ws_size >= need_sort) {
        unsigned* cnt    = (unsigned*)((char*)d_ws + off_cnt);
        float*    ws_vox = (float*)((char*)d_ws + off_vox);
        unsigned* cursor = (unsigned*)((char*)d_ws + off_cur);
        int*      vid    = (int*)((char*)d_ws + off_vid);
        int*      vid_s  = (int*)((char*)d_ws + off_vs);
        __half*   ft     = (__half*)((char*)d_ws + off_ft);

        // atomic segsum needs cnt AND ws_vox zeroed (contiguous region)
        hipMemsetAsync((char*)d_ws + off_cnt, 0, cnt_bytes + vox_bytes, stream);

        mean1_kernel<<<dim3(64, NB), 256, 0, stream>>>(coords, part);
        mean2_kernel<<<NB, 64, 0, stream>>>(part, meanf);
        max1_kernel <<<dim3(64, NB), 256, 0, stream>>>(coords, meanf, partmax);
        max2_kernel <<<NB, 64, 0, stream>>>(partmax, denomv);
        nc_vid_kernel<<<dim3(NPTS / 1024, NB), 256, 0, stream>>>(coords, meanf, denomv,
                                                                 ncout, vid, cnt);
        scan1_kernel<<<dim3(32, NB), 256, 0, stream>>>(cnt, cursor, tot);
        scan2_kernel<<<1, 512, 0, stream>>>(tot);
        scan3_kernel<<<dim3(32, NB), 256, 0, stream>>>(cursor, tot);
        permute_kernel<<<dim3(NPTS / 64, NB), 256, 0, stream>>>(feats, vid, cursor, ft, vid_s);
        segsum_kernel <<<dim3(NPTS / 256, NB), 256, 0, stream>>>(ft, vid_s, ws_vox);
        normalize_t_kernel<<<dim3(R3 / 64, NB), 256, 0, stream>>>(ws_vox, cnt, voxout);
    } else if (ws_size >= need_vm) {
        float* cntf   = (float*)((char*)d_ws + off_cnt);
        float* ws_vox = (float*)((char*)d_ws + off_vox);
        hipMemsetAsync((char*)d_ws + off_cnt, 0, cnt_bytes + vox_bytes, stream);
        mean1_kernel<<<dim3(64, NB), 256, 0, stream>>>(coords, part);
        mean2_kernel<<<NB, 64, 0, stream>>>(part, meanf);
        max1_kernel <<<dim3(64, NB), 256, 0, stream>>>(coords, meanf, partmax);
        max2_kernel <<<NB, 64, 0, stream>>>(partmax, denomv);
        scatter_vm_kernel<<<dim3(NPTS / 64, NB), 256, 0, stream>>>(
            feats, coords, meanf, denomv, ws_vox, ncout, cntf);
        normalize_tf_kernel<<<dim3(R3 / 64, NB), 256, 0, stream>>>(ws_vox, cntf, voxout);
    }
}

// Round 11
// 319.774 us; speedup vs baseline: 1.4303x; 1.0146x over previous
//
#include <hip/hip_runtime.h>
#include <hip/hip_fp16.h>

#define RR 32
#define R3 32768           // 32^3
#define NPTS 65536
#define NCH 64
#define NB 8

// ---------------- atomic-free reductions ----------------

// grid (64, NB), block 256; each block reduces 1024 points -> part[(b*64+blk)*3+axis]
__global__ void mean1_kernel(const float* __restrict__ coords, double* __restrict__ part) {
    __shared__ double ls[3][4];
    int b = blockIdx.y, blk = blockIdx.x;
    int t = threadIdx.x;
    const float* cb = coords + (size_t)b * 3 * NPTS;
    int base = blk * 1024 + t;
    double sx = 0.0, sy = 0.0, sz = 0.0;
#pragma unroll
    for (int k = 0; k < 4; k++) {
        int n = base + k * 256;
        sx += cb[n];
        sy += cb[NPTS + n];
        sz += cb[2 * NPTS + n];
    }
    for (int off = 32; off > 0; off >>= 1) {
        sx += __shfl_down(sx, off);
        sy += __shfl_down(sy, off);
        sz += __shfl_down(sz, off);
    }
    int wave = t >> 6;
    if ((t & 63) == 0) { ls[0][wave] = sx; ls[1][wave] = sy; ls[2][wave] = sz; }
    __syncthreads();
    if (t == 0) {
        part[((size_t)b * 64 + blk) * 3 + 0] = ls[0][0] + ls[0][1] + ls[0][2] + ls[0][3];
        part[((size_t)b * 64 + blk) * 3 + 1] = ls[1][0] + ls[1][1] + ls[1][2] + ls[1][3];
        part[((size_t)b * 64 + blk) * 3 + 2] = ls[2][0] + ls[2][1] + ls[2][2] + ls[2][3];
    }
}

// grid NB, block 64; combine 64 partials -> meanf[b*4+axis]
__global__ void mean2_kernel(const double* __restrict__ part, float* __restrict__ meanf) {
    int b = blockIdx.x, l = threadIdx.x;
    double sx = part[((size_t)b * 64 + l) * 3 + 0];
    double sy = part[((size_t)b * 64 + l) * 3 + 1];
    double sz = part[((size_t)b * 64 + l) * 3 + 2];
    for (int off = 32; off > 0; off >>= 1) {
        sx += __shfl_down(sx, off);
        sy += __shfl_down(sy, off);
        sz += __shfl_down(sz, off);
    }
    if (l == 0) {
        meanf[b * 4 + 0] = (float)(sx * (1.0 / NPTS));
        meanf[b * 4 + 1] = (float)(sy * (1.0 / NPTS));
        meanf[b * 4 + 2] = (float)(sz * (1.0 / NPTS));
    }
}

// grid (64, NB), block 256; partial max of squared dist -> partmax[b*64+blk]
__global__ void max1_kernel(const float* __restrict__ coords,
                            const float* __restrict__ meanf,
                            float* __restrict__ partmax) {
    __shared__ float ls[4];
    int b = blockIdx.y, blk = blockIdx.x;
    int t = threadIdx.x;
    float mx = meanf[b * 4 + 0], my = meanf[b * 4 + 1], mz = meanf[b * 4 + 2];
    const float* cb = coords + (size_t)b * 3 * NPTS;
    int base = blk * 1024 + t;
    float m = 0.0f;
#pragma unroll
    for (int k = 0; k < 4; k++) {
        int n = base + k * 256;
        float dx = cb[n] - mx;
        float dy = cb[NPTS + n] - my;
        float dz = cb[2 * NPTS + n] - mz;
        m = fmaxf(m, dx * dx + dy * dy + dz * dz);
    }
    for (int off = 32; off > 0; off >>= 1) m = fmaxf(m, __shfl_down(m, off));
    int wave = t >> 6;
    if ((t & 63) == 0) ls[wave] = m;
    __syncthreads();
    if (t == 0) partmax[b * 64 + blk] = fmaxf(fmaxf(ls[0], ls[1]), fmaxf(ls[2], ls[3]));
}

// grid NB, block 64; combine -> denom[b] = 2*sqrt(max)
__global__ void max2_kernel(const float* __restrict__ partmax, float* __restrict__ denom) {
    int b = blockIdx.x, l = threadIdx.x;
    float m = partmax[b * 64 + l];
    for (int off = 32; off > 0; off >>= 1) m = fmaxf(m, __shfl_down(m, off));
    if (l == 0) denom[b] = 2.0f * sqrtf(m);   // EPS = 0
}

// ---------------- sorted pipeline ----------------

// 4 points per thread, float4 IO. grid (NPTS/1024, NB) x 256.
__global__ void nc_vid_kernel(const float* __restrict__ coords,
                              const float* __restrict__ meanf,
                              const float* __restrict__ denomv,
                              float* __restrict__ ncout,
                              int* __restrict__ vid,
                              unsigned* __restrict__ cnt) {
    int b = blockIdx.y;
    int n0 = (blockIdx.x * 256 + threadIdx.x) * 4;
    float mx = meanf[b * 4 + 0], my = meanf[b * 4 + 1], mz = meanf[b * 4 + 2];
    float rden = 32.0f / denomv[b];
    const float* cb = coords + (size_t)b * 3 * NPTS;
    float4 x4 = *reinterpret_cast<const float4*>(cb + n0);
    float4 y4 = *reinterpret_cast<const float4*>(cb + NPTS + n0);
    float4 z4 = *reinterpret_cast<const float4*>(cb + 2 * NPTS + n0);
    float qx[4], qy[4], qz[4];
    qx[0] = fminf(fmaxf((x4.x - mx) * rden + 16.0f, 0.0f), 31.0f);
    qx[1] = fminf(fmaxf((x4.y - mx) * rden + 16.0f, 0.0f), 31.0f);
    qx[2] = fminf(fmaxf((x4.z - mx) * rden + 16.0f, 0.0f), 31.0f);
    qx[3] = fminf(fmaxf((x4.w - mx) * rden + 16.0f, 0.0f), 31.0f);
    qy[0] = fminf(fmaxf((y4.x - my) * rden + 16.0f, 0.0f), 31.0f);
    qy[1] = fminf(fmaxf((y4.y - my) * rden + 16.0f, 0.0f), 31.0f);
    qy[2] = fminf(fmaxf((y4.z - my) * rden + 16.0f, 0.0f), 31.0f);
    qy[3] = fminf(fmaxf((y4.w - my) * rden + 16.0f, 0.0f), 31.0f);
    qz[0] = fminf(fmaxf((z4.x - mz) * rden + 16.0f, 0.0f), 31.0f);
    qz[1] = fminf(fmaxf((z4.y - mz) * rden + 16.0f, 0.0f), 31.0f);
    qz[2] = fminf(fmaxf((z4.z - mz) * rden + 16.0f, 0.0f), 31.0f);
    qz[3] = fminf(fmaxf((z4.w - mz) * rden + 16.0f, 0.0f), 31.0f);
    float* nb_ = ncout + (size_t)b * 3 * NPTS;
    *reinterpret_cast<float4*>(nb_ + n0)             = make_float4(qx[0], qx[1], qx[2], qx[3]);
    *reinterpret_cast<float4*>(nb_ + NPTS + n0)      = make_float4(qy[0], qy[1], qy[2], qy[3]);
    *reinterpret_cast<float4*>(nb_ + 2 * NPTS + n0)  = make_float4(qz[0], qz[1], qz[2], qz[3]);
    int fl[4];
#pragma unroll
    for (int k = 0; k < 4; k++) {
        fl[k] = ((int)rintf(qx[k]) * RR + (int)rintf(qy[k])) * RR + (int)rintf(qz[k]);
        atomicAdd(&cnt[b * R3 + fl[k]], 1u);
    }
    *reinterpret_cast<int4*>(vid + b * NPTS + n0) = make_int4(fl[0], fl[1], fl[2], fl[3]);
}

// ---- 3-phase parallel scan ----
// scan1: grid (32, NB) x 256; block-local exclusive prefix over 1024 voxels.
__global__ void scan1_kernel(const unsigned* __restrict__ cnt,
                             unsigned* __restrict__ cursor,
                             unsigned* __restrict__ tot) {
    __shared__ unsigned ls[256];
    int b = blockIdx.y, blk = blockIdx.x, t = threadIdx.x;
    const unsigned* c = cnt + b * R3 + blk * 1024;
    uint4 v = *reinterpret_cast<const uint4*>(c + t * 4);
    unsigned s = v.x + v.y + v.z + v.w;
    ls[t] = s;
    __syncthreads();
    for (int d = 1; d < 256; d <<= 1) {
        unsigned x = (t >= d) ? ls[t - d] : 0u;
        __syncthreads();
        ls[t] += x;
        __syncthreads();
    }
    unsigned base = (t == 0) ? 0u : ls[t - 1];
    if (t == 255) tot[b * 32 + blk] = ls[255];
    uint4 o;
    o.x = base;
    o.y = base + v.x;
    o.z = base + v.x + v.y;
    o.w = base + v.x + v.y + v.z;
    *reinterpret_cast<uint4*>(cursor + b * R3 + blk * 1024 + t * 4) = o;
}

// scan2: 1 block x 512; wave w scans batch w's 32 block-totals -> exclusive.
__global__ void scan2_kernel(unsigned* __restrict__ tot) {
    int b = threadIdx.x >> 6;
    int lane = threadIdx.x & 63;
    unsigned v = (lane < 32) ? tot[b * 32 + lane] : 0u;
    unsigned orig = v;
    for (int d = 1; d < 32; d <<= 1) {
        unsigned x = __shfl_up(v, d);
        if (lane >= d && lane < 32) v += x;
    }
    if (lane < 32) tot[b * 32 + lane] = v - orig;   // exclusive
}

// scan3: grid (32, NB) x 256; add per-block offsets.
__global__ void scan3_kernel(unsigned* __restrict__ cursor,
                             const unsigned* __restrict__ tot) {
    int b = blockIdx.y, blk = blockIdx.x, t = threadIdx.x;
    unsigned off = tot[b * 32 + blk];
    uint4* p = reinterpret_cast<uint4*>(cursor + b * R3 + blk * 1024 + t * 4);
    uint4 v = *p;
    v.x += off; v.y += off; v.z += off; v.w += off;
    *p = v;
}

// Transpose 64x64 feature tile AND scatter rows to sorted positions (fp16).
// Grid is (NB, NPTS/64): linear workgroup id = b + blk*8, so id%8 == b and
// (assuming round-robin XCD dispatch) ALL blocks of batch b land on XCD b.
// Batch b's scattered 8MB ft window then maps to ONE L2 instead of bouncing
// across 8 incoherent L2s. Stores stay nontemporal full 128B lines.
__global__ void permute_kernel(const float* __restrict__ feats,
                               const int* __restrict__ vid,
                               unsigned* __restrict__ cursor,
                               __half* __restrict__ ft,
                               int* __restrict__ vid_sorted) {
    __shared__ float tile[64][65];
    __shared__ int spos[64];
    int b  = blockIdx.x;             // batch -> XCD affinity
    int n0 = blockIdx.y * 64;
    int t  = threadIdx.x;

    if (t < 64) {
        int flat = vid[b * NPTS + n0 + t];
        int pos = (int)atomicAdd(&cursor[b * R3 + flat], 1u);
        spos[t] = pos;
        vid_sorted[b * NPTS + pos] = flat;
    }

    const float* fb = feats + (size_t)b * NCH * NPTS + n0;
    int i  = t & 63;
    int c0w = t >> 6;
#pragma unroll
    for (int iter = 0; iter < 16; iter++) {
        int c = iter * 4 + c0w;
        tile[i][c] = fb[(size_t)c * NPTS + i];
    }
    __syncthreads();

    int wave = t >> 6;
    int lane = t & 63;
    int hp = lane >> 5;              // which point of the pair
    int c0 = (lane & 31) * 2;        // channel pair
    __half* fbase = ft + (size_t)b * NPTS * NCH;
#pragma unroll
    for (int j = 0; j < 8; j++) {
        int p = wave * 16 + j * 2 + hp;
        __half2 hv = __floats2half2_rn(tile[p][c0], tile[p][c0 + 1]);
        unsigned u = *reinterpret_cast<unsigned*>(&hv);
        __builtin_nontemporal_store(
            u, reinterpret_cast<unsigned*>(fbase + (size_t)spos[p] * NCH + c0));
    }
}

// Balanced segmented sum. Grid (NB, NPTS/256): same batch->XCD affinity so
// batch b's ws_vox atomic lines live in one L2 (no cross-XCD bouncing).
__global__ void segsum_kernel(const __half* __restrict__ ft,
                              const int* __restrict__ vid_sorted,
                              float* __restrict__ ws_vox) {
    __shared__ int sv[257];
    int b   = blockIdx.x;            // batch -> XCD affinity
    int t   = threadIdx.x;
    int bp0 = blockIdx.y * 256;

    sv[t] = vid_sorted[b * NPTS + bp0 + t];
    if (t == 0)
        sv[256] = (bp0 + 256 < NPTS) ? vid_sorted[b * NPTS + bp0 + 256] : -1;
    __syncthreads();

    int wave  = t >> 6;
    int lane  = t & 63;
    int chunk = wave * 2 + (lane >> 5);   // 0..7, 32 positions each
    int c0    = (lane & 31) * 2;          // channel pair
    int p0    = chunk * 32;

    const __half* fb = ft + ((size_t)b * NPTS + bp0 + p0) * NCH + c0;
    float* wv = ws_vox + (size_t)b * R3 * NCH + c0;

    float sx = 0.0f, sy = 0.0f;
    int vcur = sv[p0];
#pragma unroll
    for (int k = 0; k < 32; k++) {
        unsigned u = __builtin_nontemporal_load(
            reinterpret_cast<const unsigned*>(fb + (size_t)k * NCH));
        __half2 h = *reinterpret_cast<__half2*>(&u);
        float2 f = __half22float2(h);
        sx += f.x;
        sy += f.y;
        int vnext = sv[p0 + k + 1];       // p0+32 valid: sv has 257 entries
        if (vnext != vcur) {
            atomicAdd(wv + (size_t)vcur * NCH, sx);
            atomicAdd(wv + (size_t)vcur * NCH + 1, sy);
            sx = 0.0f;
            sy = 0.0f;
            vcur = vnext;
        }
    }
    if (sx != 0.0f || sy != 0.0f) {       // tail partial (adds 0 if none)
        atomicAdd(wv + (size_t)vcur * NCH, sx);
        atomicAdd(wv + (size_t)vcur * NCH + 1, sy);
    }
}

// ws_vox [B][R3][C] -> voxout [B][C][R3], divide by count, skip empty voxels.
// float4 both phases: read 4 channels/lane, write 4 voxels/lane.
__global__ void normalize_t_kernel(const float* __restrict__ ws_vox,
                                   const unsigned* __restrict__ cnt,
                                   float* __restrict__ voxout) {
    __shared__ float tile[64][65];    // [c][vi], skewed
    int b  = blockIdx.y;
    int v0 = blockIdx.x * 64;
    int t  = threadIdx.x;
    __shared__ float cinv[64];
    __shared__ unsigned scnt[64];
    if (t < 64) {
        unsigned c = cnt[b * R3 + v0 + t];
        scnt[t] = c;
        cinv[t] = 1.0f / fmaxf((float)c, 1.0f);
    }
    __syncthreads();
    const float* src = ws_vox + ((size_t)b * R3 + v0) * NCH;
#pragma unroll
    for (int iter = 0; iter < 4; iter++) {
        int f4 = iter * 256 + t;          // 1024 float4s total
        int vi = f4 >> 4;                 // voxel
        int c4 = (f4 & 15) * 4;           // channel quad
        float4 v;
        if (scnt[vi]) {
            v = *reinterpret_cast<const float4*>(src + (size_t)vi * NCH + c4);
            float ci = cinv[vi];
            v.x *= ci; v.y *= ci; v.z *= ci; v.w *= ci;
        } else {
            v = make_float4(0.0f, 0.0f, 0.0f, 0.0f);
        }
        tile[c4][vi] = v.x;
        tile[c4 + 1][vi] = v.y;
        tile[c4 + 2][vi] = v.z;
        tile[c4 + 3][vi] = v.w;
    }
    __syncthreads();
    float* dst = voxout + (size_t)b * NCH * R3 + v0;
#pragma unroll
    for (int iter = 0; iter < 4; iter++) {
        int f4 = iter * 256 + t;
        int c  = f4 >> 4;                 // channel
        int v4 = (f4 & 15) * 4;           // voxel quad
        float4 o = make_float4(tile[c][v4], tile[c][v4 + 1],
                               tile[c][v4 + 2], tile[c][v4 + 3]);
        *reinterpret_cast<float4*>(dst + (size_t)c * R3 + v4) = o;
    }
}

// ---------------- fallback: voxel-major atomics ----------------

__global__ void scatter_vm_kernel(const float* __restrict__ feats,
                                  const float* __restrict__ coords,
                                  const float* __restrict__ meanf,
                                  const float* __restrict__ denomv,
                                  float* __restrict__ ws_vox,
                                  float* __restrict__ ncout,
                                  float* __restrict__ cnt) {
    __shared__ float tile[64][65];
    __shared__ int   sflat[64];
    int b  = blockIdx.y;
    int n0 = blockIdx.x * 64;
    int t  = threadIdx.x;
    if (t < 64) {
        int n = n0 + t;
        float mx = meanf[b * 4 + 0], my = meanf[b * 4 + 1], mz = meanf[b * 4 + 2];
        float denom = denomv[b];
        const float* cb = coords + (size_t)b * 3 * NPTS;
        float dx = cb[n] - mx;
        float dy = cb[NPTS + n] - my;
        float dz = cb[2 * NPTS + n] - mz;
        float qx = fminf(fmaxf((dx / denom + 0.5f) * 32.0f, 0.0f), 31.0f);
        float qy = fminf(fmaxf((dy / denom + 0.5f) * 32.0f, 0.0f), 31.0f);
        float qz = fminf(fmaxf((dz / denom + 0.5f) * 32.0f, 0.0f), 31.0f);
        float* nb_ = ncout + (size_t)b * 3 * NPTS;
        nb_[n] = qx;
        nb_[NPTS + n] = qy;
        nb_[2 * NPTS + n] = qz;
        int flat = ((int)rintf(qx) * RR + (int)rintf(qy)) * RR + (int)rintf(qz);
        sflat[t] = flat;
        atomicAdd(&cnt[b * R3 + flat], 1.0f);
    }
    const float* fb = feats + (size_t)b * NCH * NPTS + n0;
    int i = t & 63;
    int c0 = t >> 6;
#pragma unroll
    for (int iter = 0; iter < 16; iter++) {
        int c = iter * 4 + c0;
        tile[i][c] = fb[(size_t)c * NPTS + i];
    }
    __syncthreads();
    int wave = t >> 6;
    int lane = t & 63;
#pragma unroll
    for (int k = 0; k < 16; k++) {
        int p = wave * 16 + k;
        float v = tile[p][lane];
        size_t base = ((size_t)b * R3 + sflat[p]) * NCH;
        atomicAdd(&ws_vox[base + lane], v);
    }
}

__global__ void normalize_tf_kernel(const float* __restrict__ ws_vox,
                                    const float* __restrict__ cnt,
                                    float* __restrict__ voxout) {
    __shared__ float tile[64][65];
    __shared__ float cinv[64];
    int b  = blockIdx.y;
    int v0 = blockIdx.x * 64;
    int t  = threadIdx.x;
    if (t < 64) cinv[t] = 1.0f / fmaxf(cnt[b * R3 + v0 + t], 1.0f);
    __syncthreads();
    const float* src = ws_vox + ((size_t)b * R3 + v0) * NCH;
    int c = t & 63;
    int w = t >> 6;
#pragma unroll
    for (int iter = 0; iter < 16; iter++) {
        int vi = iter * 4 + w;
        tile[c][vi] = src[(size_t)vi * NCH + c] * cinv[vi];
    }
    __syncthreads();
    float* dst = voxout + (size_t)b * NCH * R3 + v0;
    int vi = t & 63;
#pragma unroll
    for (int iter = 0; iter < 16; iter++) {
        int cc = iter * 4 + w;
        dst[(size_t)cc * R3 + vi] = tile[cc][vi];
    }
}

extern "C" void kernel_launch(void* const* d_in, const int* in_sizes, int n_in,
                              void* d_out, int out_size, void* d_ws, size_t ws_size,
                              hipStream_t stream) {
    const float* feats  = (const float*)d_in[0];   // [8,64,65536]
    const float* coords = (const float*)d_in[1];   // [8,3,65536]
    float* out = (float*)d_out;
    float* voxout = out;                                   // [8,64,32768]
    float* ncout  = out + (size_t)NB * NCH * R3;           // [8,3,65536]

    // small scratch (no zeroing needed — all plain-written before read)
    double* part    = (double*)d_ws;                               // [NB*64*3] = 12 KB
    float*  partmax = (float*)((char*)d_ws + 12544);               // [NB*64]   = 2 KB
    float*  meanf   = (float*)((char*)d_ws + 14592);               // [NB*4]
    float*  denomv  = (float*)((char*)d_ws + 14720);               // [NB]
    unsigned* tot   = (unsigned*)((char*)d_ws + 14848);            // [NB*32] = 1 KB

    const size_t off_cnt   = 16384;
    const size_t cnt_bytes = (size_t)NB * R3 * 4;               // 1 MB
    const size_t off_vox   = off_cnt + cnt_bytes;
    const size_t vox_bytes = (size_t)NB * R3 * NCH * 4;         // 64 MB
    const size_t off_cur   = off_vox + vox_bytes;
    const size_t off_vid   = off_cur + cnt_bytes;
    const size_t vid_bytes = (size_t)NB * NPTS * 4;             // 2 MB
    const size_t off_vs    = off_vid + vid_bytes;
    const size_t off_ft    = off_vs + vid_bytes;
    const size_t ft_bytes  = (size_t)NB * NPTS * NCH * 2;       // 64 MB fp16
    const size_t need_sort = off_ft + ft_bytes;                 // ~135 MB
    const size_t need_vm   = off_vox + vox_bytes;               // ~65 MB

    if (ws_size >= need_sort) {
        unsigned* cnt    = (unsigned*)((char*)d_ws + off_cnt);
        float*    ws_vox = (float*)((char*)d_ws + off_vox);
        unsigned* cursor = (unsigned*)((char*)d_ws + off_cur);
        int*      vid    = (int*)((char*)d_ws + off_vid);
        int*      vid_s  = (int*)((char*)d_ws + off_vs);
        __half*   ft     = (__half*)((char*)d_ws + off_ft);

        // atomic segsum needs cnt AND ws_vox zeroed (contiguous region)
        hipMemsetAsync((char*)d_ws + off_cnt, 0, cnt_bytes + vox_bytes, stream);

        mean1_kernel<<<dim3(64, NB), 256, 0, stream>>>(coords, part);
        mean2_kernel<<<NB, 64, 0, stream>>>(part, meanf);
        max1_kernel <<<dim3(64, NB), 256, 0, stream>>>(coords, meanf, partmax);
        max2_kernel <<<NB, 64, 0, stream>>>(partmax, denomv);
        nc_vid_kernel<<<dim3(NPTS / 1024, NB), 256, 0, stream>>>(coords, meanf, denomv,
                                                                 ncout, vid, cnt);
        scan1_kernel<<<dim3(32, NB), 256, 0, stream>>>(cnt, cursor, tot);
        scan2_kernel<<<1, 512, 0, stream>>>(tot);
        scan3_kernel<<<dim3(32, NB), 256, 0, stream>>>(cursor, tot);
        // batch->XCD affinity grids: blockIdx.x = batch (linear id % 8 == b)
        permute_kernel<<<dim3(NB, NPTS / 64), 256, 0, stream>>>(feats, vid, cursor, ft, vid_s);
        segsum_kernel <<<dim3(NB, NPTS / 256), 256, 0, stream>>>(ft, vid_s, ws_vox);
        normalize_t_kernel<<<dim3(R3 / 64, NB), 256, 0, stream>>>(ws_vox, cnt, voxout);
    } else if (ws_size >= need_vm) {
        float* cntf   = (float*)((char*)d_ws + off_cnt);
        float* ws_vox = (float*)((char*)d_ws + off_vox);
        hipMemsetAsync((char*)d_ws + off_cnt, 0, cnt_bytes + vox_bytes, stream);
        mean1_kernel<<<dim3(64, NB), 256, 0, stream>>>(coords, part);
        mean2_kernel<<<NB, 64, 0, stream>>>(part, meanf);
        max1_kernel <<<dim3(64, NB), 256, 0, stream>>>(coords, meanf, partmax);
        max2_kernel <<<NB, 64, 0, stream>>>(partmax, denomv);
        scatter_vm_kernel<<<dim3(NPTS / 64, NB), 256, 0, stream>>>(
            feats, coords, meanf, denomv, ws_vox, ncout, cntf);
        normalize_tf_kernel<<<dim3(R3 / 64, NB), 256, 0, stream>>>(ws_vox, cntf, voxout);
    }
}